// Round 1
// baseline (5581.012 us; speedup 1.0000x reference)
//
#include <hip/hip_runtime.h>
#include <hip/hip_bf16.h>

#define LEAK 0.2f

__device__ __forceinline__ float wave_sum(float p) {
#pragma unroll
  for (int m = 1; m < 64; m <<= 1) p += __shfl_xor(p, m);
  return p;
}

// ---------------- Dense GEMM: out[M,64] = A[M,K] @ W[K,64] + b ----------------
// Block 256 thr, 64 rows/block, K-chunk 128. Thread: 4 rows x 4 cols.
__global__ __launch_bounds__(256) void gemm_bias(
    const float* __restrict__ A, const float* __restrict__ W,
    const float* __restrict__ bias, float* __restrict__ out, int M, int K)
{
  __shared__ float As[64 * 132];
  __shared__ float Wt[64 * 132];
  const int tid = threadIdx.x;
  const int lane = tid & 63, wave = tid >> 6;
  const int c0 = lane & 15;          // cols c0, c0+16, c0+32, c0+48
  const int rsub = lane >> 4;        // 0..3
  const int rloc = wave * 16 + rsub * 4;
  const int rowBase = blockIdx.x * 64;

  float acc[4][4];
#pragma unroll
  for (int r = 0; r < 4; ++r)
#pragma unroll
    for (int i = 0; i < 4; ++i) acc[r][i] = 0.f;

  for (int kc = 0; kc < K; kc += 128) {
    __syncthreads();
    // stage A chunk [64 rows][128 k]
#pragma unroll
    for (int j = 0; j < 8; ++j) {
      int idx = tid + j * 256;
      int row = idx >> 5, k4 = idx & 31;
      int gr = rowBase + row;
      int gk = kc + k4 * 4;
      float4 av = make_float4(0.f, 0.f, 0.f, 0.f);
      if (gr < M && gk < K) av = *(const float4*)(A + (size_t)gr * K + gk);
      *(float4*)(As + row * 132 + k4 * 4) = av;
    }
    // stage W chunk transposed: Wt[col][k]
#pragma unroll
    for (int j = 0; j < 8; ++j) {
      int idx = tid + j * 256;
      int k = idx >> 4, c4 = (idx & 15) * 4;
      int gk = kc + k;
      float4 wv = make_float4(0.f, 0.f, 0.f, 0.f);
      if (gk < K) wv = *(const float4*)(W + (size_t)gk * 64 + c4);
      Wt[(c4 + 0) * 132 + k] = wv.x;
      Wt[(c4 + 1) * 132 + k] = wv.y;
      Wt[(c4 + 2) * 132 + k] = wv.z;
      Wt[(c4 + 3) * 132 + k] = wv.w;
    }
    __syncthreads();
#pragma unroll 4
    for (int kk = 0; kk < 128; kk += 4) {
      float4 a[4], w[4];
#pragma unroll
      for (int r = 0; r < 4; ++r) a[r] = *(const float4*)(As + (rloc + r) * 132 + kk);
#pragma unroll
      for (int i = 0; i < 4; ++i) w[i] = *(const float4*)(Wt + (c0 + 16 * i) * 132 + kk);
#pragma unroll
      for (int r = 0; r < 4; ++r)
#pragma unroll
        for (int i = 0; i < 4; ++i)
          acc[r][i] += a[r].x * w[i].x + a[r].y * w[i].y + a[r].z * w[i].z + a[r].w * w[i].w;
    }
  }
  float bv[4];
#pragma unroll
  for (int i = 0; i < 4; ++i) bv[i] = bias[c0 + 16 * i];
#pragma unroll
  for (int r = 0; r < 4; ++r) {
    int gr = rowBase + rloc + r;
    if (gr < M) {
#pragma unroll
      for (int i = 0; i < 4; ++i)
        out[(size_t)gr * 64 + c0 + 16 * i] = acc[r][i] + bv[i];
    }
  }
}

// ---------------- Row-wise L2 normalize in place ----------------
__global__ void l2norm_rows(float* __restrict__ x, int M)
{
  int lane = threadIdx.x & 63;
  int wid = (blockIdx.x * blockDim.x + threadIdx.x) >> 6;
  int nw = (gridDim.x * blockDim.x) >> 6;
  for (int n = wid; n < M; n += nw) {
    float v = x[(size_t)n * 64 + lane];
    float ss = wave_sum(v * v);
    float nrm = fmaxf(sqrtf(ss), 1e-12f);
    x[(size_t)n * 64 + lane] = v / nrm;
  }
}

// ---------------- SpMM via per-edge atomics ----------------
// out[rows[e], :] += scale * vals[e] * x[cols[e], :], x = virtual concat(lo, hi)
__global__ __launch_bounds__(256) void spmm_atomic(
    const int* __restrict__ rows, const int* __restrict__ cols,
    const float* __restrict__ vals,
    const float* __restrict__ lo, const float* __restrict__ hi, int user,
    float* __restrict__ out, float scale, int nedges)
{
  int lane = threadIdx.x & 63;
  int wid = (blockIdx.x * blockDim.x + threadIdx.x) >> 6;
  int nw = (gridDim.x * blockDim.x) >> 6;
  for (int base = wid * 64; base < nedges; base += nw * 64) {
    int e = base + lane;
    int c = 0, r = 0;
    float v = 0.f;
    if (e < nedges) { c = cols[e]; r = rows[e]; v = vals[e] * scale; }
    int cnt = min(64, nedges - base);
    for (int i = 0; i < cnt; ++i) {
      int ci = __shfl(c, i);
      int ri = __shfl(r, i);
      float vi = __shfl(v, i);
      const float* src = (ci < user) ? (lo + (size_t)ci * 64)
                                     : (hi + (size_t)(ci - user) * 64);
      atomicAdd(out + (size_t)ri * 64 + lane, vi * src[lane]);
    }
  }
}

// ---------------- modal mix ----------------
__global__ void modal_kernel(const float* __restrict__ u, const float* __restrict__ imgn,
                             const float* __restrict__ acc, const float* __restrict__ stxt,
                             const float* __restrict__ t1, const float* __restrict__ t2,
                             const float* __restrict__ mw,
                             float* __restrict__ modal, float* __restrict__ total,
                             int user, int ntot)
{
  size_t idx = (size_t)blockIdx.x * blockDim.x + threadIdx.x;
  size_t tot = (size_t)ntot * 64;
  if (idx >= tot) return;
  int n = (int)(idx >> 6);
  float m0 = mw[0], m1 = mw[1];
  float mx = fmaxf(m0, m1);
  float e0 = expf(m0 - mx), e1 = expf(m1 - mx);
  float w0 = e0 / (e0 + e1), w1 = e1 / (e0 + e1);
  float bi = (n < user) ? u[idx] : imgn[idx - (size_t)user * 64];
  float ei = bi + acc[idx];
  float et = t1[idx] + t2[idx] + stxt[idx];
  float m = w0 * ei + w1 * et;
  modal[idx] = m;
  total[idx] = m;
}

// ---------------- GCN attention scores: es[n] = exp(E[n,:]·attw), sum via atomics --------
__global__ void scores_kernel(const float* __restrict__ E, const float* __restrict__ attw,
                              float* __restrict__ es, float* __restrict__ sumslot, int ntot)
{
  int lane = threadIdx.x & 63;
  int wid = (blockIdx.x * blockDim.x + threadIdx.x) >> 6;
  int nw = (gridDim.x * blockDim.x) >> 6;
  float aw = attw[lane];
  float acc = 0.f;
  for (int n = wid; n < ntot; n += nw) {
    float p = E[(size_t)n * 64 + lane] * aw;
    p = wave_sum(p);
    float ex = expf(p);
    if (lane == 0) es[n] = ex;
    acc += ex;
  }
  if (lane == 0) atomicAdd(sumslot, acc);
}

// ---------------- apply attention + leaky relu, accumulate total ----------------
__global__ void apply_att(const float* __restrict__ E, const float* __restrict__ es,
                          const float* __restrict__ sumslot,
                          float* __restrict__ cur, float* __restrict__ total, int ntot)
{
  size_t idx = (size_t)blockIdx.x * blockDim.x + threadIdx.x;
  size_t tot = (size_t)ntot * 64;
  if (idx >= tot) return;
  int n = (int)(idx >> 6);
  float att = es[n] / sumslot[0];
  float x = E[idx] * att;
  x = (x >= 0.f) ? x : LEAK * x;
  cur[idx] = x;
  total[idx] += x;
}

// ---------------- final: out += 0.5 * l2norm(modal) rowwise ----------------
__global__ void final_norm_add(const float* __restrict__ modal, float* __restrict__ out, int ntot)
{
  int lane = threadIdx.x & 63;
  int wid = (blockIdx.x * blockDim.x + threadIdx.x) >> 6;
  int nw = (gridDim.x * blockDim.x) >> 6;
  for (int n = wid; n < ntot; n += nw) {
    float m = modal[(size_t)n * 64 + lane];
    float ss = wave_sum(m * m);
    float inv = 0.5f / fmaxf(sqrtf(ss), 1e-12f);
    out[(size_t)n * 64 + lane] += m * inv;
  }
}

extern "C" void kernel_launch(void* const* d_in, const int* in_sizes, int n_in,
                              void* d_out, int out_size, void* d_ws, size_t ws_size,
                              hipStream_t stream)
{
  const int*   adj_r = (const int*)d_in[0];
  const int*   adj_c = (const int*)d_in[1];
  const float* adj_v = (const float*)d_in[2];
  const int*   img_r = (const int*)d_in[3];
  const int*   img_c = (const int*)d_in[4];
  const float* img_v = (const float*)d_in[5];
  const int*   txt_r = (const int*)d_in[6];
  const int*   txt_c = (const int*)d_in[7];
  const float* txt_v = (const float*)d_in[8];
  const float* u_emb = (const float*)d_in[9];
  const float* i_emb = (const float*)d_in[10];
  const float* img_W = (const float*)d_in[11];
  const float* img_b = (const float*)d_in[12];
  const float* txt_W = (const float*)d_in[13];
  const float* txt_b = (const float*)d_in[14];
  const float* mw    = (const float*)d_in[15];
  const float* att_w = (const float*)d_in[16];
  const float* img_e = (const float*)d_in[17];
  const float* txt_e = (const float*)d_in[18];

  const int nedges = in_sizes[0];
  const int user = in_sizes[9] / 64;
  const int item = in_sizes[10] / 64;
  const int ntot = user + item;
  const int Kimg = in_sizes[11] / 64;
  const int Ktxt = in_sizes[13] / 64;
  const int Mimg = in_sizes[17] / Kimg;
  const int Mtxt = in_sizes[18] / Ktxt;

  float* ws = (float*)d_ws;
  size_t off = 0;
  float* imgn  = ws + off; off += (size_t)Mimg * 64;
  float* txtn  = ws + off; off += (size_t)Mtxt * 64;
  float* accB  = ws + off; off += (size_t)ntot * 64;   // spmm(adj,e0) + 0.2 spmm(img,e0)
  float* stxt  = ws + off; off += (size_t)ntot * 64;   // 0.2 spmm(txt,e0)
  float* t1    = ws + off; off += (size_t)ntot * 64;
  float* modal = ws + off; off += (size_t)ntot * 64;
  float* es    = ws + off; off += (size_t)ntot;
  float* sums  = ws + off; off += 8;
  float* t2    = (float*)d_out;   // reused: consumed by modal_kernel which then overwrites it
  float* total = (float*)d_out;
  float* E   = accB;  // reused after modal
  float* cur = stxt;  // reused after modal

  const size_t nbytes = (size_t)ntot * 64 * sizeof(float);
  hipMemsetAsync(sums, 0, 8 * sizeof(float), stream);

  // modality projection + row l2norm
  gemm_bias<<<(Mimg + 63) / 64, 256, 0, stream>>>(img_e, img_W, img_b, imgn, Mimg, Kimg);
  gemm_bias<<<(Mtxt + 63) / 64, 256, 0, stream>>>(txt_e, txt_W, txt_b, txtn, Mtxt, Ktxt);
  l2norm_rows<<<256, 256, 0, stream>>>(imgn, Mimg);
  l2norm_rows<<<256, 256, 0, stream>>>(txtn, Mtxt);

  hipMemsetAsync(accB, 0, nbytes, stream);
  hipMemsetAsync(stxt, 0, nbytes, stream);
  hipMemsetAsync(t1,   0, nbytes, stream);
  hipMemsetAsync(t2,   0, nbytes, stream);

  const int SB = 4096;
  spmm_atomic<<<SB, 256, 0, stream>>>(adj_r, adj_c, adj_v, u_emb, i_emb, user, accB, 1.0f, nedges);
  spmm_atomic<<<SB, 256, 0, stream>>>(img_r, img_c, img_v, u_emb, i_emb, user, accB, 0.2f, in_sizes[3]);
  spmm_atomic<<<SB, 256, 0, stream>>>(txt_r, txt_c, txt_v, u_emb, i_emb, user, stxt, 0.2f, in_sizes[6]);
  spmm_atomic<<<SB, 256, 0, stream>>>(adj_r, adj_c, adj_v, u_emb, txtn, user, t1, 1.0f, nedges);
  spmm_atomic<<<SB, 256, 0, stream>>>(adj_r, adj_c, adj_v, t1, i_emb, user, t2, 1.0f, nedges);

  const int blk = (int)(((size_t)ntot * 64 + 255) / 256);
  modal_kernel<<<blk, 256, 0, stream>>>(u_emb, imgn, accB, stxt, t1, t2, mw, modal, total, user, ntot);

  for (int l = 0; l < 2; ++l) {
    hipMemsetAsync(E, 0, nbytes, stream);
    const float* src = (l == 0) ? modal : cur;
    spmm_atomic<<<SB, 256, 0, stream>>>(adj_r, adj_c, adj_v, src, src + (size_t)user * 64, user,
                                        E, 1.0f, nedges);
    scores_kernel<<<256, 256, 0, stream>>>(E, att_w + (size_t)l * 64, es, sums + l, ntot);
    apply_att<<<blk, 256, 0, stream>>>(E, es, sums + l, cur, total, ntot);
  }
  final_norm_add<<<256, 256, 0, stream>>>(modal, total, ntot);
}

// Round 3
// 3415.022 us; speedup vs baseline: 1.6343x; 1.6343x over previous
//
#include <hip/hip_runtime.h>
#include <hip/hip_bf16.h>

#define LEAK 0.2f

__device__ __forceinline__ float wave_sum(float p) {
#pragma unroll
  for (int m = 1; m < 64; m <<= 1) p += __shfl_xor(p, m);
  return p;
}

__device__ __forceinline__ int wave_scan_incl(int v) {
  int lane = threadIdx.x & 63;
#pragma unroll
  for (int d = 1; d < 64; d <<= 1) {
    int t = __shfl_up(v, d);
    if (lane >= d) v += t;
  }
  return v;
}

// ---------------- Dense GEMM: out[M,64] = A[M,K] @ W[K,64] + b ----------------
__global__ __launch_bounds__(256) void gemm_bias(
    const float* __restrict__ A, const float* __restrict__ W,
    const float* __restrict__ bias, float* __restrict__ out, int M, int K)
{
  __shared__ float As[64 * 132];
  __shared__ float Wt[64 * 132];
  const int tid = threadIdx.x;
  const int lane = tid & 63, wave = tid >> 6;
  const int c0 = lane & 15;
  const int rsub = lane >> 4;
  const int rloc = wave * 16 + rsub * 4;
  const int rowBase = blockIdx.x * 64;

  float acc[4][4];
#pragma unroll
  for (int r = 0; r < 4; ++r)
#pragma unroll
    for (int i = 0; i < 4; ++i) acc[r][i] = 0.f;

  for (int kc = 0; kc < K; kc += 128) {
    __syncthreads();
#pragma unroll
    for (int j = 0; j < 8; ++j) {
      int idx = tid + j * 256;
      int row = idx >> 5, k4 = idx & 31;
      int gr = rowBase + row;
      int gk = kc + k4 * 4;
      float4 av = make_float4(0.f, 0.f, 0.f, 0.f);
      if (gr < M && gk < K) av = *(const float4*)(A + (size_t)gr * K + gk);
      *(float4*)(As + row * 132 + k4 * 4) = av;
    }
#pragma unroll
    for (int j = 0; j < 8; ++j) {
      int idx = tid + j * 256;
      int k = idx >> 4, c4 = (idx & 15) * 4;
      int gk = kc + k;
      float4 wv = make_float4(0.f, 0.f, 0.f, 0.f);
      if (gk < K) wv = *(const float4*)(W + (size_t)gk * 64 + c4);
      Wt[(c4 + 0) * 132 + k] = wv.x;
      Wt[(c4 + 1) * 132 + k] = wv.y;
      Wt[(c4 + 2) * 132 + k] = wv.z;
      Wt[(c4 + 3) * 132 + k] = wv.w;
    }
    __syncthreads();
#pragma unroll 4
    for (int kk = 0; kk < 128; kk += 4) {
      float4 a[4], w[4];
#pragma unroll
      for (int r = 0; r < 4; ++r) a[r] = *(const float4*)(As + (rloc + r) * 132 + kk);
#pragma unroll
      for (int i = 0; i < 4; ++i) w[i] = *(const float4*)(Wt + (c0 + 16 * i) * 132 + kk);
#pragma unroll
      for (int r = 0; r < 4; ++r)
#pragma unroll
        for (int i = 0; i < 4; ++i)
          acc[r][i] += a[r].x * w[i].x + a[r].y * w[i].y + a[r].z * w[i].z + a[r].w * w[i].w;
    }
  }
  float bv[4];
#pragma unroll
  for (int i = 0; i < 4; ++i) bv[i] = bias[c0 + 16 * i];
#pragma unroll
  for (int r = 0; r < 4; ++r) {
    int gr = rowBase + rloc + r;
    if (gr < M) {
#pragma unroll
      for (int i = 0; i < 4; ++i)
        out[(size_t)gr * 64 + c0 + 16 * i] = acc[r][i] + bv[i];
    }
  }
}

// ---------------- Row-wise L2 normalize in place ----------------
__global__ void l2norm_rows(float* __restrict__ x, int M)
{
  int lane = threadIdx.x & 63;
  int wid = (blockIdx.x * blockDim.x + threadIdx.x) >> 6;
  int nw = (gridDim.x * blockDim.x) >> 6;
  for (int n = wid; n < M; n += nw) {
    float v = x[(size_t)n * 64 + lane];
    float ss = wave_sum(v * v);
    float nrm = fmaxf(sqrtf(ss), 1e-12f);
    x[(size_t)n * 64 + lane] = v / nrm;
  }
}

// ================= CSR build =================
__global__ void count_rows(const int* __restrict__ rows, int nedges, int* __restrict__ deg)
{
  int idx = blockIdx.x * blockDim.x + threadIdx.x;
  int stride = gridDim.x * blockDim.x;
  for (int e = idx; e < nedges; e += stride) atomicAdd(&deg[rows[e]], 1);
}

__global__ void block_reduce_deg(const int* __restrict__ deg, int n, int* __restrict__ bsum)
{
  __shared__ int wt[4];
  int idx = blockIdx.x * 256 + threadIdx.x;
  int v = (idx < n) ? deg[idx] : 0;
#pragma unroll
  for (int m = 1; m < 64; m <<= 1) v += __shfl_xor(v, m);
  if ((threadIdx.x & 63) == 0) wt[threadIdx.x >> 6] = v;
  __syncthreads();
  if (threadIdx.x == 0) bsum[blockIdx.x] = wt[0] + wt[1] + wt[2] + wt[3];
}

// single wave, exclusive scan of bsum in place
__global__ void scan_bsums(int* __restrict__ bsum, int nb)
{
  int lane = threadIdx.x;
  int carry = 0;
  for (int base = 0; base < nb; base += 64) {
    int idx = base + lane;
    int v = (idx < nb) ? bsum[idx] : 0;
    int sv = wave_scan_incl(v);
    if (idx < nb) bsum[idx] = sv - v + carry;
    carry += __shfl(sv, 63);
  }
}

__global__ void block_scan_write(const int* __restrict__ deg, const int* __restrict__ boff,
                                 int n, int* __restrict__ rowptr, int* __restrict__ cursor)
{
  __shared__ int wt[4];
  int idx = blockIdx.x * 256 + threadIdx.x;
  int v = (idx < n) ? deg[idx] : 0;
  int sv = wave_scan_incl(v);
  if ((threadIdx.x & 63) == 63) wt[threadIdx.x >> 6] = sv;
  __syncthreads();
  int w = threadIdx.x >> 6;
  int wo = 0;
#pragma unroll
  for (int k = 0; k < 4; ++k) if (k < w) wo += wt[k];
  int excl = sv - v + wo + boff[blockIdx.x];
  if (idx < n) { rowptr[idx] = excl; cursor[idx] = excl; }
  if (idx == n - 1) rowptr[n] = excl + v;
}

__global__ void scatter_edges(const int* __restrict__ rows, const int* __restrict__ cols,
                              const float* __restrict__ vals, int nedges,
                              int* __restrict__ cursor, int* __restrict__ ecol,
                              float* __restrict__ eval)
{
  int idx = blockIdx.x * blockDim.x + threadIdx.x;
  int stride = gridDim.x * blockDim.x;
  for (int e = idx; e < nedges; e += stride) {
    int r = rows[e];
    int pos = atomicAdd(&cursor[r], 1);
    ecol[pos] = cols[e];
    eval[pos] = vals[e];
  }
}

// ---------------- CSR SpMM, row-per-wave, optional fused attention scores ------
__global__ __launch_bounds__(256) void spmm_csr(
    const int* __restrict__ rowptr, const int* __restrict__ ecol,
    const float* __restrict__ eval,
    const float* __restrict__ lo, const float* __restrict__ hi, int user,
    float* __restrict__ out, float scale, int beta, int ntot,
    const float* __restrict__ attw, float* __restrict__ es, float* __restrict__ sumslot)
{
  const int lane = threadIdx.x & 63;
  int wid = (blockIdx.x * blockDim.x + threadIdx.x) >> 6;
  int nw = (gridDim.x * blockDim.x) >> 6;
  float aw = attw ? attw[lane] : 0.f;
  float sacc = 0.f;
  for (int r = wid; r < ntot; r += nw) {
    int s = rowptr[r], e_end = rowptr[r + 1];
    float acc = 0.f;
    for (int p = s; p < e_end; p += 64) {
      int e = p + lane;
      int c = 0; float v = 0.f;
      if (e < e_end) { c = ecol[e]; v = eval[e]; }
      int cnt = min(64, e_end - p);
      for (int i = 0; i < cnt; ++i) {
        int ci = __shfl(c, i);
        float vi = __shfl(v, i);
        const float* src = (ci < user) ? (lo + (size_t)ci * 64)
                                       : (hi + (size_t)(ci - user) * 64);
        acc = fmaf(vi, src[lane], acc);
      }
    }
    acc *= scale;
    if (beta) acc += out[(size_t)r * 64 + lane];
    out[(size_t)r * 64 + lane] = acc;
    if (attw) {
      float pdot = wave_sum(acc * aw);
      float ex = expf(pdot);
      if (lane == 0) es[r] = ex;
      sacc += ex;
    }
  }
  if (attw && lane == 0) atomicAdd(sumslot, sacc);
}

// ---------------- SpMM via per-edge atomics (fallback) ----------------
__global__ __launch_bounds__(256) void spmm_atomic(
    const int* __restrict__ rows, const int* __restrict__ cols,
    const float* __restrict__ vals,
    const float* __restrict__ lo, const float* __restrict__ hi, int user,
    float* __restrict__ out, float scale, int nedges)
{
  int lane = threadIdx.x & 63;
  int wid = (blockIdx.x * blockDim.x + threadIdx.x) >> 6;
  int nw = (gridDim.x * blockDim.x) >> 6;
  for (int base = wid * 64; base < nedges; base += nw * 64) {
    int e = base + lane;
    int c = 0, r = 0;
    float v = 0.f;
    if (e < nedges) { c = cols[e]; r = rows[e]; v = vals[e] * scale; }
    int cnt = min(64, nedges - base);
    for (int i = 0; i < cnt; ++i) {
      int ci = __shfl(c, i);
      int ri = __shfl(r, i);
      float vi = __shfl(v, i);
      const float* src = (ci < user) ? (lo + (size_t)ci * 64)
                                     : (hi + (size_t)(ci - user) * 64);
      atomicAdd(out + (size_t)ri * 64 + lane, vi * src[lane]);
    }
  }
}

// ---------------- modal mix ----------------
__global__ void modal_kernel(const float* __restrict__ u, const float* __restrict__ imgn,
                             const float* __restrict__ acc, const float* __restrict__ stxt,
                             const float* __restrict__ t1, const float* __restrict__ t2,
                             const float* __restrict__ mw,
                             float* __restrict__ modal, float* __restrict__ total,
                             int user, int ntot)
{
  size_t idx = (size_t)blockIdx.x * blockDim.x + threadIdx.x;
  size_t tot = (size_t)ntot * 64;
  if (idx >= tot) return;
  int n = (int)(idx >> 6);
  float m0 = mw[0], m1 = mw[1];
  float mx = fmaxf(m0, m1);
  float e0 = expf(m0 - mx), e1 = expf(m1 - mx);
  float w0 = e0 / (e0 + e1), w1 = e1 / (e0 + e1);
  float bi = (n < user) ? u[idx] : imgn[idx - (size_t)user * 64];
  float ei = bi + acc[idx];
  float et = t1[idx] + t2[idx] + stxt[idx];
  float m = w0 * ei + w1 * et;
  modal[idx] = m;
  total[idx] = m;
}

// ---------------- scores (fallback, non-fused) ----------------
__global__ void scores_kernel(const float* __restrict__ E, const float* __restrict__ attw,
                              float* __restrict__ es, float* __restrict__ sumslot, int ntot)
{
  int lane = threadIdx.x & 63;
  int wid = (blockIdx.x * blockDim.x + threadIdx.x) >> 6;
  int nw = (gridDim.x * blockDim.x) >> 6;
  float aw = attw[lane];
  float acc = 0.f;
  for (int n = wid; n < ntot; n += nw) {
    float p = E[(size_t)n * 64 + lane] * aw;
    p = wave_sum(p);
    float ex = expf(p);
    if (lane == 0) es[n] = ex;
    acc += ex;
  }
  if (lane == 0) atomicAdd(sumslot, acc);
}

// ---------------- apply attention + leaky relu, accumulate total ----------------
__global__ void apply_att(const float* __restrict__ E, const float* __restrict__ es,
                          const float* __restrict__ sumslot,
                          float* __restrict__ cur, float* __restrict__ total, int ntot)
{
  size_t idx = (size_t)blockIdx.x * blockDim.x + threadIdx.x;
  size_t tot = (size_t)ntot * 64;
  if (idx >= tot) return;
  int n = (int)(idx >> 6);
  float att = es[n] / sumslot[0];
  float x = E[idx] * att;
  x = (x >= 0.f) ? x : LEAK * x;
  cur[idx] = x;
  total[idx] += x;
}

// ---------------- final: out += 0.5 * l2norm(modal) rowwise ----------------
__global__ void final_norm_add(const float* __restrict__ modal, float* __restrict__ out, int ntot)
{
  int lane = threadIdx.x & 63;
  int wid = (blockIdx.x * blockDim.x + threadIdx.x) >> 6;
  int nw = (gridDim.x * blockDim.x) >> 6;
  for (int n = wid; n < ntot; n += nw) {
    float m = modal[(size_t)n * 64 + lane];
    float ss = wave_sum(m * m);
    float inv = 0.5f / fmaxf(sqrtf(ss), 1e-12f);
    out[(size_t)n * 64 + lane] += m * inv;
  }
}

extern "C" void kernel_launch(void* const* d_in, const int* in_sizes, int n_in,
                              void* d_out, int out_size, void* d_ws, size_t ws_size,
                              hipStream_t stream)
{
  const int*   adj_r = (const int*)d_in[0];
  const int*   adj_c = (const int*)d_in[1];
  const float* adj_v = (const float*)d_in[2];
  const int*   img_r = (const int*)d_in[3];
  const int*   img_c = (const int*)d_in[4];
  const float* img_v = (const float*)d_in[5];
  const int*   txt_r = (const int*)d_in[6];
  const int*   txt_c = (const int*)d_in[7];
  const float* txt_v = (const float*)d_in[8];
  const float* u_emb = (const float*)d_in[9];
  const float* i_emb = (const float*)d_in[10];
  const float* img_W = (const float*)d_in[11];
  const float* img_b = (const float*)d_in[12];
  const float* txt_W = (const float*)d_in[13];
  const float* txt_b = (const float*)d_in[14];
  const float* mw    = (const float*)d_in[15];
  const float* att_w = (const float*)d_in[16];
  const float* img_e = (const float*)d_in[17];
  const float* txt_e = (const float*)d_in[18];

  const int E1 = in_sizes[0], E2 = in_sizes[3], E3 = in_sizes[6];
  const int user = in_sizes[9] / 64;
  const int item = in_sizes[10] / 64;
  const int ntot = user + item;
  const int Kimg = in_sizes[11] / 64;
  const int Ktxt = in_sizes[13] / 64;
  const int Mimg = in_sizes[17] / Kimg;
  const int Mtxt = in_sizes[18] / Ktxt;

  char* basep = (char*)d_ws;
  size_t off = 0;
  auto alc = [&](size_t nb) -> char* {
    char* p = basep + off;
    off = (off + nb + 255) & ~(size_t)255;
    return p;
  };

  float* imgn  = (float*)alc((size_t)Mimg * 64 * 4);
  float* txtn  = (float*)alc((size_t)Mtxt * 64 * 4);
  float* accB  = (float*)alc((size_t)ntot * 64 * 4);
  float* stxt  = (float*)alc((size_t)ntot * 64 * 4);
  float* t1    = (float*)alc((size_t)ntot * 64 * 4);
  float* modal = (float*)alc((size_t)ntot * 64 * 4);
  float* es    = (float*)alc((size_t)ntot * 4);
  float* sums  = (float*)alc(256);
  int*   deg   = (int*)alc((size_t)ntot * 4);
  int*   bsum  = (int*)alc(4096);
  int*   rpA   = (int*)alc((size_t)(ntot + 1) * 4);
  int*   curA  = (int*)alc((size_t)ntot * 4);
  int*   ecolA = (int*)alc((size_t)E1 * 4);
  float* evalA = (float*)alc((size_t)E1 * 4);
  size_t adj_need = off;
  const int Emax = (E2 > E3) ? E2 : E3;
  int*   rpT   = (int*)alc((size_t)(ntot + 1) * 4);
  int*   curT  = (int*)alc((size_t)ntot * 4);
  int*   ecolT = (int*)alc((size_t)Emax * 4);
  float* evalT = (float*)alc((size_t)Emax * 4);
  size_t full_need = off;

  const bool useA = ws_size >= adj_need;
  const bool useT = ws_size >= full_need;

  float* t2    = (float*)d_out;  // consumed by modal_kernel which then overwrites it
  float* total = (float*)d_out;
  float* E   = accB;  // reused after modal
  float* cur = stxt;  // reused after modal

  const size_t nbytes = (size_t)ntot * 64 * sizeof(float);
  hipMemsetAsync(sums, 0, 256, stream);

  // modality projection + row l2norm
  gemm_bias<<<(Mimg + 63) / 64, 256, 0, stream>>>(img_e, img_W, img_b, imgn, Mimg, Kimg);
  gemm_bias<<<(Mtxt + 63) / 64, 256, 0, stream>>>(txt_e, txt_W, txt_b, txtn, Mtxt, Ktxt);
  l2norm_rows<<<256, 256, 0, stream>>>(imgn, Mimg);
  l2norm_rows<<<256, 256, 0, stream>>>(txtn, Mtxt);

  const int nb = (ntot + 255) / 256;
  auto build = [&](const int* rr, const int* cc, const float* vv, int ne,
                   int* rp, int* curp, int* ec, float* ev) {
    hipMemsetAsync(deg, 0, (size_t)ntot * 4, stream);
    count_rows<<<1024, 256, 0, stream>>>(rr, ne, deg);
    block_reduce_deg<<<nb, 256, 0, stream>>>(deg, ntot, bsum);
    scan_bsums<<<1, 64, 0, stream>>>(bsum, nb);
    block_scan_write<<<nb, 256, 0, stream>>>(deg, bsum, ntot, rp, curp);
    scatter_edges<<<1024, 256, 0, stream>>>(rr, cc, vv, ne, curp, ec, ev);
  };

  const int SG = 2048;  // spmm grid
  const int SB = 4096;  // atomic fallback grid
  const int blk = (int)(((size_t)ntot * 64 + 255) / 256);

  if (useA) {
    build(adj_r, adj_c, adj_v, E1, rpA, curA, ecolA, evalA);
    // accB = spmm(adj, e0)
    spmm_csr<<<SG, 256, 0, stream>>>(rpA, ecolA, evalA, u_emb, i_emb, user,
                                     accB, 1.0f, 0, ntot, nullptr, nullptr, nullptr);
    // accB += 0.2 * spmm(img, e0)
    if (useT) {
      build(img_r, img_c, img_v, E2, rpT, curT, ecolT, evalT);
      spmm_csr<<<SG, 256, 0, stream>>>(rpT, ecolT, evalT, u_emb, i_emb, user,
                                       accB, 0.2f, 1, ntot, nullptr, nullptr, nullptr);
    } else {
      spmm_atomic<<<SB, 256, 0, stream>>>(img_r, img_c, img_v, u_emb, i_emb, user,
                                          accB, 0.2f, E2);
    }
    // stxt = 0.2 * spmm(txt, e0)
    if (useT) {
      build(txt_r, txt_c, txt_v, E3, rpT, curT, ecolT, evalT);
      spmm_csr<<<SG, 256, 0, stream>>>(rpT, ecolT, evalT, u_emb, i_emb, user,
                                       stxt, 0.2f, 0, ntot, nullptr, nullptr, nullptr);
    } else {
      hipMemsetAsync(stxt, 0, nbytes, stream);
      spmm_atomic<<<SB, 256, 0, stream>>>(txt_r, txt_c, txt_v, u_emb, i_emb, user,
                                          stxt, 0.2f, E3);
    }
    // t1 = spmm(adj, concat(u, txtn)) ; t2 = spmm(adj, concat(t1_lo, i))
    spmm_csr<<<SG, 256, 0, stream>>>(rpA, ecolA, evalA, u_emb, txtn, user,
                                     t1, 1.0f, 0, ntot, nullptr, nullptr, nullptr);
    spmm_csr<<<SG, 256, 0, stream>>>(rpA, ecolA, evalA, t1, i_emb, user,
                                     t2, 1.0f, 0, ntot, nullptr, nullptr, nullptr);
  } else {
    // full atomic fallback (round-1 path)
    hipMemsetAsync(accB, 0, nbytes, stream);
    hipMemsetAsync(stxt, 0, nbytes, stream);
    hipMemsetAsync(t1,   0, nbytes, stream);
    hipMemsetAsync(t2,   0, nbytes, stream);
    spmm_atomic<<<SB, 256, 0, stream>>>(adj_r, adj_c, adj_v, u_emb, i_emb, user, accB, 1.0f, E1);
    spmm_atomic<<<SB, 256, 0, stream>>>(img_r, img_c, img_v, u_emb, i_emb, user, accB, 0.2f, E2);
    spmm_atomic<<<SB, 256, 0, stream>>>(txt_r, txt_c, txt_v, u_emb, i_emb, user, stxt, 0.2f, E3);
    spmm_atomic<<<SB, 256, 0, stream>>>(adj_r, adj_c, adj_v, u_emb, txtn, user, t1, 1.0f, E1);
    spmm_atomic<<<SB, 256, 0, stream>>>(adj_r, adj_c, adj_v, t1, i_emb, user, t2, 1.0f, E1);
  }

  modal_kernel<<<blk, 256, 0, stream>>>(u_emb, imgn, accB, stxt, t1, t2, mw,
                                        modal, total, user, ntot);

  for (int l = 0; l < 2; ++l) {
    const float* src = (l == 0) ? modal : cur;
    if (useA) {
      spmm_csr<<<SG, 256, 0, stream>>>(rpA, ecolA, evalA, src, src + (size_t)user * 64, user,
                                       E, 1.0f, 0, ntot, att_w + (size_t)l * 64, es, sums + l);
    } else {
      hipMemsetAsync(E, 0, nbytes, stream);
      spmm_atomic<<<SB, 256, 0, stream>>>(adj_r, adj_c, adj_v, src, src + (size_t)user * 64,
                                          user, E, 1.0f, E1);
      scores_kernel<<<256, 256, 0, stream>>>(E, att_w + (size_t)l * 64, es, sums + l, ntot);
    }
    apply_att<<<blk, 256, 0, stream>>>(E, es, sums + l, cur, total, ntot);
  }
  final_norm_add<<<256, 256, 0, stream>>>(modal, total, ntot);
}

// Round 8
// 2971.138 us; speedup vs baseline: 1.8784x; 1.1494x over previous
//
#include <hip/hip_runtime.h>
#include <hip/hip_bf16.h>

#define LEAK 0.2f

__device__ __forceinline__ float wave_sum(float p) {
#pragma unroll
  for (int m = 1; m < 64; m <<= 1) p += __shfl_xor(p, m);
  return p;
}

__device__ __forceinline__ int wave_scan_incl(int v) {
  int lane = threadIdx.x & 63;
#pragma unroll
  for (int d = 1; d < 64; d <<= 1) {
    int t = __shfl_up(v, d);
    if (lane >= d) v += t;
  }
  return v;
}

// ---------------- Dense GEMM: out[M,64] = A[M,K] @ W[K,64] + b ----------------
__global__ __launch_bounds__(256) void gemm_bias(
    const float* __restrict__ A, const float* __restrict__ W,
    const float* __restrict__ bias, float* __restrict__ out, int M, int K)
{
  __shared__ float As[64 * 132];
  __shared__ float Wt[64 * 132];
  const int tid = threadIdx.x;
  const int lane = tid & 63, wave = tid >> 6;
  const int c0 = lane & 15;
  const int rsub = lane >> 4;
  const int rloc = wave * 16 + rsub * 4;
  const int rowBase = blockIdx.x * 64;

  float acc[4][4];
#pragma unroll
  for (int r = 0; r < 4; ++r)
#pragma unroll
    for (int i = 0; i < 4; ++i) acc[r][i] = 0.f;

  for (int kc = 0; kc < K; kc += 128) {
    __syncthreads();
#pragma unroll
    for (int j = 0; j < 8; ++j) {
      int idx = tid + j * 256;
      int row = idx >> 5, k4 = idx & 31;
      int gr = rowBase + row;
      int gk = kc + k4 * 4;
      float4 av = make_float4(0.f, 0.f, 0.f, 0.f);
      if (gr < M && gk < K) av = *(const float4*)(A + (size_t)gr * K + gk);
      *(float4*)(As + row * 132 + k4 * 4) = av;
    }
#pragma unroll
    for (int j = 0; j < 8; ++j) {
      int idx = tid + j * 256;
      int k = idx >> 4, c4 = (idx & 15) * 4;
      int gk = kc + k;
      float4 wv = make_float4(0.f, 0.f, 0.f, 0.f);
      if (gk < K) wv = *(const float4*)(W + (size_t)gk * 64 + c4);
      Wt[(c4 + 0) * 132 + k] = wv.x;
      Wt[(c4 + 1) * 132 + k] = wv.y;
      Wt[(c4 + 2) * 132 + k] = wv.z;
      Wt[(c4 + 3) * 132 + k] = wv.w;
    }
    __syncthreads();
#pragma unroll 4
    for (int kk = 0; kk < 128; kk += 4) {
      float4 a[4], w[4];
#pragma unroll
      for (int r = 0; r < 4; ++r) a[r] = *(const float4*)(As + (rloc + r) * 132 + kk);
#pragma unroll
      for (int i = 0; i < 4; ++i) w[i] = *(const float4*)(Wt + (c0 + 16 * i) * 132 + kk);
#pragma unroll
      for (int r = 0; r < 4; ++r)
#pragma unroll
        for (int i = 0; i < 4; ++i)
          acc[r][i] += a[r].x * w[i].x + a[r].y * w[i].y + a[r].z * w[i].z + a[r].w * w[i].w;
    }
  }
  float bv[4];
#pragma unroll
  for (int i = 0; i < 4; ++i) bv[i] = bias[c0 + 16 * i];
#pragma unroll
  for (int r = 0; r < 4; ++r) {
    int gr = rowBase + rloc + r;
    if (gr < M) {
#pragma unroll
      for (int i = 0; i < 4; ++i)
        out[(size_t)gr * 64 + c0 + 16 * i] = acc[r][i] + bv[i];
    }
  }
}

// ---------------- Row-wise L2 normalize in place ----------------
__global__ void l2norm_rows(float* __restrict__ x, int M)
{
  int lane = threadIdx.x & 63;
  int wid = (blockIdx.x * blockDim.x + threadIdx.x) >> 6;
  int nw = (gridDim.x * blockDim.x) >> 6;
  for (int n = wid; n < M; n += nw) {
    float v = x[(size_t)n * 64 + lane];
    float ss = wave_sum(v * v);
    float nrm = fmaxf(sqrtf(ss), 1e-12f);
    x[(size_t)n * 64 + lane] = v / nrm;
  }
}

// ================= CSR build =================
__global__ void count_rows(const int* __restrict__ rows, int nedges, int* __restrict__ deg)
{
  int idx = blockIdx.x * blockDim.x + threadIdx.x;
  int stride = gridDim.x * blockDim.x;
  for (int e = idx; e < nedges; e += stride) atomicAdd(&deg[rows[e]], 1);
}

__global__ void block_reduce_deg(const int* __restrict__ deg, int n, int* __restrict__ bsum)
{
  __shared__ int wt[4];
  int idx = blockIdx.x * 256 + threadIdx.x;
  int v = (idx < n) ? deg[idx] : 0;
#pragma unroll
  for (int m = 1; m < 64; m <<= 1) v += __shfl_xor(v, m);
  if ((threadIdx.x & 63) == 0) wt[threadIdx.x >> 6] = v;
  __syncthreads();
  if (threadIdx.x == 0) bsum[blockIdx.x] = wt[0] + wt[1] + wt[2] + wt[3];
}

// single wave, exclusive scan of bsum in place
__global__ void scan_bsums(int* __restrict__ bsum, int nb)
{
  int lane = threadIdx.x;
  int carry = 0;
  for (int base = 0; base < nb; base += 64) {
    int idx = base + lane;
    int v = (idx < nb) ? bsum[idx] : 0;
    int sv = wave_scan_incl(v);
    if (idx < nb) bsum[idx] = sv - v + carry;
    carry += __shfl(sv, 63);
  }
}

__global__ void block_scan_write(const int* __restrict__ deg, const int* __restrict__ boff,
                                 int n, int* __restrict__ rowptr, int* __restrict__ cursor)
{
  __shared__ int wt[4];
  int idx = blockIdx.x * 256 + threadIdx.x;
  int v = (idx < n) ? deg[idx] : 0;
  int sv = wave_scan_incl(v);
  if ((threadIdx.x & 63) == 63) wt[threadIdx.x >> 6] = sv;
  __syncthreads();
  int w = threadIdx.x >> 6;
  int wo = 0;
#pragma unroll
  for (int k = 0; k < 4; ++k) if (k < w) wo += wt[k];
  int excl = sv - v + wo + boff[blockIdx.x];
  if (idx < n) { rowptr[idx] = excl; cursor[idx] = excl; }
  if (idx == n - 1) rowptr[n] = excl + v;
}

// paired scatter: one 8B write per edge instead of two 4B writes
__global__ __launch_bounds__(256) void scatter_edges_pair(
    const int* __restrict__ rows, const int* __restrict__ cols,
    const float* __restrict__ vals, int nedges,
    int* __restrict__ cursor, int2* __restrict__ epair)
{
  int idx = blockIdx.x * blockDim.x + threadIdx.x;
  int stride = gridDim.x * blockDim.x;
  for (int e = idx; e < nedges; e += stride) {
    int r = rows[e];
    int pos = atomicAdd(&cursor[r], 1);
    epair[pos] = make_int2(cols[e], __float_as_int(vals[e]));
  }
}

// ---------------- CSR SpMM, row-per-wave, uniform edge loads, unroll x4 -------
__global__ __launch_bounds__(256) void spmm_csr(
    const int* __restrict__ rowptr, const int2* __restrict__ ep,
    const float* __restrict__ lo, const float* __restrict__ hi, int user,
    float* __restrict__ out, float scale, int beta, int ntot,
    const float* __restrict__ attw, float* __restrict__ es, float* __restrict__ sumslot)
{
  const int lane = threadIdx.x & 63;
  int wid = (blockIdx.x * blockDim.x + threadIdx.x) >> 6;
  int nw = (gridDim.x * blockDim.x) >> 6;
  float aw = attw ? attw[lane] : 0.f;
  float sacc = 0.f;
  for (int r0 = wid; r0 < ntot; r0 += nw) {
    const int r = __builtin_amdgcn_readfirstlane(r0);
    int s = rowptr[r], e_end = rowptr[r + 1];
    float a0 = 0.f, a1 = 0.f, a2 = 0.f, a3 = 0.f;
    int e = s;
    for (; e + 4 <= e_end; e += 4) {
      int2 p0 = ep[e], p1 = ep[e + 1], p2 = ep[e + 2], p3 = ep[e + 3];
      const float* s0 = (p0.x < user) ? (lo + (size_t)p0.x * 64) : (hi + (size_t)(p0.x - user) * 64);
      const float* s1 = (p1.x < user) ? (lo + (size_t)p1.x * 64) : (hi + (size_t)(p1.x - user) * 64);
      const float* s2 = (p2.x < user) ? (lo + (size_t)p2.x * 64) : (hi + (size_t)(p2.x - user) * 64);
      const float* s3 = (p3.x < user) ? (lo + (size_t)p3.x * 64) : (hi + (size_t)(p3.x - user) * 64);
      float g0 = s0[lane], g1 = s1[lane], g2 = s2[lane], g3 = s3[lane];
      a0 = fmaf(__int_as_float(p0.y), g0, a0);
      a1 = fmaf(__int_as_float(p1.y), g1, a1);
      a2 = fmaf(__int_as_float(p2.y), g2, a2);
      a3 = fmaf(__int_as_float(p3.y), g3, a3);
    }
    for (; e < e_end; ++e) {
      int2 p = ep[e];
      const float* sp = (p.x < user) ? (lo + (size_t)p.x * 64) : (hi + (size_t)(p.x - user) * 64);
      a0 = fmaf(__int_as_float(p.y), sp[lane], a0);
    }
    float acc = ((a0 + a1) + (a2 + a3)) * scale;
    if (beta) acc += out[(size_t)r * 64 + lane];
    out[(size_t)r * 64 + lane] = acc;
    if (attw) {
      float pdot = wave_sum(acc * aw);
      float ex = expf(pdot);
      if (lane == 0) es[r] = ex;
      sacc += ex;
    }
  }
  if (attw && lane == 0) atomicAdd(sumslot, sacc);
}

// ---- Dual CSR SpMM: same matrix, two dense inputs sharing the lo half -------
// outA = A @ concat(lo, hiA) ; outB = A @ concat(lo, hiB)
__global__ __launch_bounds__(256) void spmm_csr_dual(
    const int* __restrict__ rowptr, const int2* __restrict__ ep,
    const float* __restrict__ lo, const float* __restrict__ hiA,
    const float* __restrict__ hiB, int user,
    float* __restrict__ outA, float* __restrict__ outB, int ntot)
{
  const int lane = threadIdx.x & 63;
  int wid = (blockIdx.x * blockDim.x + threadIdx.x) >> 6;
  int nw = (gridDim.x * blockDim.x) >> 6;
  for (int r0 = wid; r0 < ntot; r0 += nw) {
    const int r = __builtin_amdgcn_readfirstlane(r0);
    int s = rowptr[r], e_end = rowptr[r + 1];
    float a0 = 0.f, a1 = 0.f, b0 = 0.f, b1 = 0.f;
    int e = s;
    for (; e + 2 <= e_end; e += 2) {
      int2 p0 = ep[e], p1 = ep[e + 1];
      const float* sa0 = (p0.x < user) ? (lo + (size_t)p0.x * 64) : (hiA + (size_t)(p0.x - user) * 64);
      const float* sb0 = (p0.x < user) ? (lo + (size_t)p0.x * 64) : (hiB + (size_t)(p0.x - user) * 64);
      const float* sa1 = (p1.x < user) ? (lo + (size_t)p1.x * 64) : (hiA + (size_t)(p1.x - user) * 64);
      const float* sb1 = (p1.x < user) ? (lo + (size_t)p1.x * 64) : (hiB + (size_t)(p1.x - user) * 64);
      float ga0 = sa0[lane], gb0 = sb0[lane], ga1 = sa1[lane], gb1 = sb1[lane];
      float v0 = __int_as_float(p0.y), v1 = __int_as_float(p1.y);
      a0 = fmaf(v0, ga0, a0);
      b0 = fmaf(v0, gb0, b0);
      a1 = fmaf(v1, ga1, a1);
      b1 = fmaf(v1, gb1, b1);
    }
    for (; e < e_end; ++e) {
      int2 p = ep[e];
      const float* sa = (p.x < user) ? (lo + (size_t)p.x * 64) : (hiA + (size_t)(p.x - user) * 64);
      const float* sb = (p.x < user) ? (lo + (size_t)p.x * 64) : (hiB + (size_t)(p.x - user) * 64);
      float v = __int_as_float(p.y);
      a0 = fmaf(v, sa[lane], a0);
      b0 = fmaf(v, sb[lane], b0);
    }
    outA[(size_t)r * 64 + lane] = a0 + a1;
    outB[(size_t)r * 64 + lane] = b0 + b1;
  }
}

// ---------------- SpMM via per-edge atomics (fallback) ----------------
__global__ __launch_bounds__(256) void spmm_atomic(
    const int* __restrict__ rows, const int* __restrict__ cols,
    const float* __restrict__ vals,
    const float* __restrict__ lo, const float* __restrict__ hi, int user,
    float* __restrict__ out, float scale, int nedges)
{
  int lane = threadIdx.x & 63;
  int wid = (blockIdx.x * blockDim.x + threadIdx.x) >> 6;
  int nw = (gridDim.x * blockDim.x) >> 6;
  for (int base = wid * 64; base < nedges; base += nw * 64) {
    int e = base + lane;
    int c = 0, r = 0;
    float v = 0.f;
    if (e < nedges) { c = cols[e]; r = rows[e]; v = vals[e] * scale; }
    int cnt = min(64, nedges - base);
    for (int i = 0; i < cnt; ++i) {
      int ci = __shfl(c, i);
      int ri = __shfl(r, i);
      float vi = __shfl(v, i);
      const float* src = (ci < user) ? (lo + (size_t)ci * 64)
                                     : (hi + (size_t)(ci - user) * 64);
      atomicAdd(out + (size_t)ri * 64 + lane, vi * src[lane]);
    }
  }
}

// ---------------- modal mix ----------------
__global__ void modal_kernel(const float* __restrict__ u, const float* __restrict__ imgn,
                             const float* __restrict__ acc, const float* __restrict__ stxt,
                             const float* __restrict__ t1, const float* __restrict__ t2,
                             const float* __restrict__ mw,
                             float* __restrict__ modal, float* __restrict__ total,
                             int user, int ntot)
{
  size_t idx = (size_t)blockIdx.x * blockDim.x + threadIdx.x;
  size_t tot = (size_t)ntot * 64;
  if (idx >= tot) return;
  int n = (int)(idx >> 6);
  float m0 = mw[0], m1 = mw[1];
  float mx = fmaxf(m0, m1);
  float e0 = expf(m0 - mx), e1 = expf(m1 - mx);
  float w0 = e0 / (e0 + e1), w1 = e1 / (e0 + e1);
  float bi = (n < user) ? u[idx] : imgn[idx - (size_t)user * 64];
  float ei = bi + acc[idx];
  float et = t1[idx] + t2[idx] + stxt[idx];
  float m = w0 * ei + w1 * et;
  modal[idx] = m;
  total[idx] = m;
}

// ---------------- scores (fallback, non-fused) ----------------
__global__ void scores_kernel(const float* __restrict__ E, const float* __restrict__ attw,
                              float* __restrict__ es, float* __restrict__ sumslot, int ntot)
{
  int lane = threadIdx.x & 63;
  int wid = (blockIdx.x * blockDim.x + threadIdx.x) >> 6;
  int nw = (gridDim.x * blockDim.x) >> 6;
  float aw = attw[lane];
  float acc = 0.f;
  for (int n = wid; n < ntot; n += nw) {
    float p = E[(size_t)n * 64 + lane] * aw;
    p = wave_sum(p);
    float ex = expf(p);
    if (lane == 0) es[n] = ex;
    acc += ex;
  }
  if (lane == 0) atomicAdd(sumslot, acc);
}

// ---------------- apply attention + leaky relu, accumulate total ----------------
__global__ void apply_att(const float* __restrict__ E, const float* __restrict__ es,
                          const float* __restrict__ sumslot,
                          float* __restrict__ cur, float* __restrict__ total, int ntot)
{
  size_t idx = (size_t)blockIdx.x * blockDim.x + threadIdx.x;
  size_t tot = (size_t)ntot * 64;
  if (idx >= tot) return;
  int n = (int)(idx >> 6);
  float att = es[n] / sumslot[0];
  float x = E[idx] * att;
  x = (x >= 0.f) ? x : LEAK * x;
  cur[idx] = x;
  total[idx] += x;
}

// ---------------- final: out += 0.5 * l2norm(modal) rowwise ----------------
__global__ void final_norm_add(const float* __restrict__ modal, float* __restrict__ out, int ntot)
{
  int lane = threadIdx.x & 63;
  int wid = (blockIdx.x * blockDim.x + threadIdx.x) >> 6;
  int nw = (gridDim.x * blockDim.x) >> 6;
  for (int n = wid; n < ntot; n += nw) {
    float m = modal[(size_t)n * 64 + lane];
    float ss = wave_sum(m * m);
    float inv = 0.5f / fmaxf(sqrtf(ss), 1e-12f);
    out[(size_t)n * 64 + lane] += m * inv;
  }
}

extern "C" void kernel_launch(void* const* d_in, const int* in_sizes, int n_in,
                              void* d_out, int out_size, void* d_ws, size_t ws_size,
                              hipStream_t stream)
{
  const int*   adj_r = (const int*)d_in[0];
  const int*   adj_c = (const int*)d_in[1];
  const float* adj_v = (const float*)d_in[2];
  const int*   img_r = (const int*)d_in[3];
  const int*   img_c = (const int*)d_in[4];
  const float* img_v = (const float*)d_in[5];
  const int*   txt_r = (const int*)d_in[6];
  const int*   txt_c = (const int*)d_in[7];
  const float* txt_v = (const float*)d_in[8];
  const float* u_emb = (const float*)d_in[9];
  const float* i_emb = (const float*)d_in[10];
  const float* img_W = (const float*)d_in[11];
  const float* img_b = (const float*)d_in[12];
  const float* txt_W = (const float*)d_in[13];
  const float* txt_b = (const float*)d_in[14];
  const float* mw    = (const float*)d_in[15];
  const float* att_w = (const float*)d_in[16];
  const float* img_e = (const float*)d_in[17];
  const float* txt_e = (const float*)d_in[18];

  const int E1 = in_sizes[0], E2 = in_sizes[3], E3 = in_sizes[6];
  const int user = in_sizes[9] / 64;
  const int item = in_sizes[10] / 64;
  const int ntot = user + item;
  const int Kimg = in_sizes[11] / 64;
  const int Ktxt = in_sizes[13] / 64;
  const int Mimg = in_sizes[17] / Kimg;
  const int Mtxt = in_sizes[18] / Ktxt;

  char* basep = (char*)d_ws;
  size_t off = 0;
  auto alc = [&](size_t nb) -> char* {
    char* p = basep + off;
    off = (off + nb + 255) & ~(size_t)255;
    return p;
  };

  float* imgn  = (float*)alc((size_t)Mimg * 64 * 4);
  float* txtn  = (float*)alc((size_t)Mtxt * 64 * 4);
  float* accB  = (float*)alc((size_t)ntot * 64 * 4);
  float* stxt  = (float*)alc((size_t)ntot * 64 * 4);
  float* t1    = (float*)alc((size_t)ntot * 64 * 4);
  float* modal = (float*)alc((size_t)ntot * 64 * 4);
  float* es    = (float*)alc((size_t)ntot * 4);
  float* sums  = (float*)alc(256);
  int*   deg   = (int*)alc((size_t)ntot * 4);
  int*   bsum  = (int*)alc(4096);
  int*   rpA   = (int*)alc((size_t)(ntot + 1) * 4);
  int*   curA  = (int*)alc((size_t)ntot * 4);
  int2*  epA   = (int2*)alc((size_t)E1 * 8);
  size_t adj_need = off;
  const int Emax = (E2 > E3) ? E2 : E3;
  int*   rpT   = (int*)alc((size_t)(ntot + 1) * 4);
  int*   curT  = (int*)alc((size_t)ntot * 4);
  int2*  epT   = (int2*)alc((size_t)Emax * 8);
  size_t full_need = off;

  const bool useA = ws_size >= adj_need;
  const bool useT = ws_size >= full_need;

  float* t2    = (float*)d_out;  // consumed by modal_kernel which then overwrites it
  float* total = (float*)d_out;
  float* E   = accB;  // reused after modal
  float* cur = stxt;  // reused after modal

  const size_t nbytes = (size_t)ntot * 64 * sizeof(float);
  hipMemsetAsync(sums, 0, 256, stream);

  // modality projection + row l2norm
  gemm_bias<<<(Mimg + 63) / 64, 256, 0, stream>>>(img_e, img_W, img_b, imgn, Mimg, Kimg);
  gemm_bias<<<(Mtxt + 63) / 64, 256, 0, stream>>>(txt_e, txt_W, txt_b, txtn, Mtxt, Ktxt);
  l2norm_rows<<<256, 256, 0, stream>>>(imgn, Mimg);
  l2norm_rows<<<256, 256, 0, stream>>>(txtn, Mtxt);

  const int nb = (ntot + 255) / 256;
  auto build = [&](const int* rr, const int* cc, const float* vv, int ne,
                   int* rp, int* curp, int2* ep) {
    hipMemsetAsync(deg, 0, (size_t)ntot * 4, stream);
    count_rows<<<2048, 256, 0, stream>>>(rr, ne, deg);
    block_reduce_deg<<<nb, 256, 0, stream>>>(deg, ntot, bsum);
    scan_bsums<<<1, 64, 0, stream>>>(bsum, nb);
    block_scan_write<<<nb, 256, 0, stream>>>(deg, bsum, ntot, rp, curp);
    scatter_edges_pair<<<4096, 256, 0, stream>>>(rr, cc, vv, ne, curp, ep);
  };

  const int SG = 4096;  // spmm grid
  const int SB = 4096;  // atomic fallback grid
  const int blk = (int)(((size_t)ntot * 64 + 255) / 256);

  if (useA) {
    build(adj_r, adj_c, adj_v, E1, rpA, curA, epA);
    // accB = spmm(adj, concat(u,i)) ; t1 = spmm(adj, concat(u, txtn)) — fused
    spmm_csr_dual<<<SG, 256, 0, stream>>>(rpA, epA, u_emb, i_emb, txtn, user,
                                          accB, t1, ntot);
    // accB += 0.2 * spmm(img, e0)
    if (useT) {
      build(img_r, img_c, img_v, E2, rpT, curT, epT);
      spmm_csr<<<SG, 256, 0, stream>>>(rpT, epT, u_emb, i_emb, user,
                                       accB, 0.2f, 1, ntot, nullptr, nullptr, nullptr);
    } else {
      spmm_atomic<<<SB, 256, 0, stream>>>(img_r, img_c, img_v, u_emb, i_emb, user,
                                          accB, 0.2f, E2);
    }
    // stxt = 0.2 * spmm(txt, e0)
    if (useT) {
      build(txt_r, txt_c, txt_v, E3, rpT, curT, epT);
      spmm_csr<<<SG, 256, 0, stream>>>(rpT, epT, u_emb, i_emb, user,
                                       stxt, 0.2f, 0, ntot, nullptr, nullptr, nullptr);
    } else {
      hipMemsetAsync(stxt, 0, nbytes, stream);
      spmm_atomic<<<SB, 256, 0, stream>>>(txt_r, txt_c, txt_v, u_emb, i_emb, user,
                                          stxt, 0.2f, E3);
    }
    // t2 = spmm(adj, concat(t1_lo, i))
    spmm_csr<<<SG, 256, 0, stream>>>(rpA, epA, t1, i_emb, user,
                                     t2, 1.0f, 0, ntot, nullptr, nullptr, nullptr);
  } else {
    // full atomic fallback (round-1 path)
    hipMemsetAsync(accB, 0, nbytes, stream);
    hipMemsetAsync(stxt, 0, nbytes, stream);
    hipMemsetAsync(t1,   0, nbytes, stream);
    hipMemsetAsync(t2,   0, nbytes, stream);
    spmm_atomic<<<SB, 256, 0, stream>>>(adj_r, adj_c, adj_v, u_emb, i_emb, user, accB, 1.0f, E1);
    spmm_atomic<<<SB, 256, 0, stream>>>(img_r, img_c, img_v, u_emb, i_emb, user, accB, 0.2f, E2);
    spmm_atomic<<<SB, 256, 0, stream>>>(txt_r, txt_c, txt_v, u_emb, i_emb, user, stxt, 0.2f, E3);
    spmm_atomic<<<SB, 256, 0, stream>>>(adj_r, adj_c, adj_v, u_emb, txtn, user, t1, 1.0f, E1);
    spmm_atomic<<<SB, 256, 0, stream>>>(adj_r, adj_c, adj_v, t1, i_emb, user, t2, 1.0f, E1);
  }

  modal_kernel<<<blk, 256, 0, stream>>>(u_emb, imgn, accB, stxt, t1, t2, mw,
                                        modal, total, user, ntot);

  for (int l = 0; l < 2; ++l) {
    const float* src = (l == 0) ? modal : cur;
    if (useA) {
      spmm_csr<<<SG, 256, 0, stream>>>(rpA, epA, src, src + (size_t)user * 64, user,
                                       E, 1.0f, 0, ntot, att_w + (size_t)l * 64, es, sums + l);
    } else {
      hipMemsetAsync(E, 0, nbytes, stream);
      spmm_atomic<<<SB, 256, 0, stream>>>(adj_r, adj_c, adj_v, src, src + (size_t)user * 64,
                                          user, E, 1.0f, E1);
      scores_kernel<<<256, 256, 0, stream>>>(E, att_w + (size_t)l * 64, es, sums + l, ntot);
    }
    apply_att<<<blk, 256, 0, stream>>>(E, es, sums + l, cur, total, ntot);
  }
  final_norm_add<<<256, 256, 0, stream>>>(modal, total, ntot);
}